// Round 15
// baseline (689.085 us; speedup 1.0000x reference)
//
#include <hip/hip_runtime.h>
#include <hip/hip_bf16.h>

// Problem constants (fixed by reference): N=262144 rows, D=64, K=512 codes.
#define N_ROWS 262144
#define DIM 64
#define KC 512
#define BLK 512                        // threads/block; 8 waves = 2/SIMD, 1 block/CU
#define RPT 2                          // rows per thread
#define LDS_FLOATS (KC * DIM + KC)     // codebook + esq = 33280 floats = 133120 B

// d_out layout — FLOAT32 (verified passing):
//   out[0]                      = loss
//   out[1 .. 1+N*D)             = quantized [N,64] row-major
//   out[1+N*D .. 1+N*D+N)       = float(encoding_indices)
//
// Numerics replicated exactly (indices must match np.argmin of f32 dists):
//   x_sq, e_sq : numpy pairwise sum, n=64 => 8-accumulator striped scheme
//   dot        : sequential fused-FMA chain, ascending j (OpenBLAS kernel)
//   d          : fl( fl(x_sq + e_sq_k) - 2*dot_k ), contraction off
//   argmin     : lexicographic min over (d_k, k) — scan-order independent,
//                EQUIVALENT to ascending-k strict-< first-min-wins.
//
// R14 was an infra failure (GPU broker timeout) — kernel never ran.
// Resubmitted unchanged.
// R13 post-mortem: RPT=4 dead (allocator caps at ~164 VGPR, partial remat,
// 449us). R8 (RPT=2, 2 waves/SIMD, 276us) is the allocator-stable optimum.
// R8's residual 100us: all 8 waves/CU run the k-loop IN PHASE — they dump
// their 32-read DS bursts simultaneously (convoy queue ~700cyc on the one
// DS pipe), then all FMA while the DS pipe idles. VALUBusy 64% fits this.
// R15: STAGGER wave phases — wave w starts at code w*64 (circular order).
// DS demand becomes temporally uniform; reads service just-in-time under
// other waves' FMA bursts. Reordered k is safe because argmin becomes the
// (d, k) lexicographic min with an exact f32 equality tiebreak; distance
// bits are identical to R8's.

// numpy pairwise sum of squares for n=64 (scalar path, PW_BLOCKSIZE=128).
__device__ __forceinline__ float np_sumsq64(const float* a) {
#pragma clang fp contract(off)
    float r[8];
#pragma unroll
    for (int j = 0; j < 8; ++j) r[j] = a[j] * a[j];
#pragma unroll
    for (int i = 8; i < 64; i += 8)
#pragma unroll
        for (int j = 0; j < 8; ++j) r[j] = r[j] + a[i + j] * a[i + j];
    return ((r[0] + r[1]) + (r[2] + r[3])) + ((r[4] + r[5]) + (r[6] + r[7]));
}

// ---- kernel 1: e_sq_k with numpy bit-exact summation ----
__global__ void esq_kernel(const float* __restrict__ cb, float* __restrict__ esq) {
    int k = blockIdx.x * blockDim.x + threadIdx.x;
    if (k < KC) esq[k] = np_sumsq64(cb + k * DIM);
}

// ---- kernel 2: main VQ — TWO rows per thread, codebook in LDS, staggered ----
__global__ __launch_bounds__(BLK)
__attribute__((amdgpu_waves_per_eu(2, 2)))   // grid-exact occupancy; 256-VGPR budget
void vq_kernel(
    const float* __restrict__ x, const float* __restrict__ cb,
    const float* __restrict__ esq_g, float* __restrict__ out,
    float* __restrict__ loss_acc)
{
    extern __shared__ float smem[];
    float* cbs  = smem;             // [512*64] codebook, k-major (global layout)
    float* esql = smem + KC * DIM;  // [512]

    const int tid  = threadIdx.x;
    const int lane = tid & 63;
    const int wid  = tid >> 6;      // wave id 0..7 (uniform per wave)
    const int row0 = blockIdx.x * (BLK * RPT) + tid;   // rows row0 and row0+BLK
    const int row1 = row0 + BLK;

    // ---- cooperative stage: 128KB codebook + 2KB esq, fully coalesced ----
    {
        const float4* g4 = reinterpret_cast<const float4*>(cb);
        float4*       s4 = reinterpret_cast<float4*>(cbs);
#pragma unroll
        for (int i = 0; i < (KC * DIM / 4) / BLK; ++i)   // 16 iters
            s4[tid + i * BLK] = g4[tid + i * BLK];
        if (tid < KC) esql[tid] = esq_g[tid];
    }

    // Two rows into 128 VGPRs — overlaps staging latency.
    float xr0[DIM], xr1[DIM];
    {
        const float4* xv0 = reinterpret_cast<const float4*>(x + (size_t)row0 * DIM);
        const float4* xv1 = reinterpret_cast<const float4*>(x + (size_t)row1 * DIM);
#pragma unroll
        for (int j = 0; j < DIM / 4; ++j) {
            float4 v0 = xv0[j], v1 = xv1[j];
            xr0[4 * j + 0] = v0.x; xr0[4 * j + 1] = v0.y;
            xr0[4 * j + 2] = v0.z; xr0[4 * j + 3] = v0.w;
            xr1[4 * j + 0] = v1.x; xr1[4 * j + 1] = v1.y;
            xr1[4 * j + 2] = v1.z; xr1[4 * j + 3] = v1.w;
        }
    }

    // numpy-exact ||x||^2 per row.
    const float xsq0 = np_sumsq64(xr0);
    const float xsq1 = np_sumsq64(xr1);

    __syncthreads();   // staging complete

    // 2 codes x 2 rows per iter = 4 independent sequential fused-FMA chains.
    // Wave w scans codes starting at w*64 (circular): DS bursts de-convoy.
    const int koff = wid * 64;
    float best0 = 3.4e38f, best1 = 3.4e38f;
    int bidx0 = 0, bidx1 = 0;
#pragma unroll 1
    for (int kl = 0; kl < KC; kl += 2) {
        const int k = (kl + koff) & (KC - 1);            // uniform per wave
        const float4* ea = reinterpret_cast<const float4*>(cbs + k * DIM);
        const float4* eb = ea + DIM / 4;
        float dot00 = 0.f, dot01 = 0.f, dot10 = 0.f, dot11 = 0.f;
#pragma unroll
        for (int c = 0; c < DIM / 4; ++c) {
            const float4 a = ea[c];
            const float4 b = eb[c];
            dot00 = fmaf(xr0[4 * c + 0], a.x, dot00);
            dot01 = fmaf(xr0[4 * c + 0], b.x, dot01);
            dot10 = fmaf(xr1[4 * c + 0], a.x, dot10);
            dot11 = fmaf(xr1[4 * c + 0], b.x, dot11);
            dot00 = fmaf(xr0[4 * c + 1], a.y, dot00);
            dot01 = fmaf(xr0[4 * c + 1], b.y, dot01);
            dot10 = fmaf(xr1[4 * c + 1], a.y, dot10);
            dot11 = fmaf(xr1[4 * c + 1], b.y, dot11);
            dot00 = fmaf(xr0[4 * c + 2], a.z, dot00);
            dot01 = fmaf(xr0[4 * c + 2], b.z, dot01);
            dot10 = fmaf(xr1[4 * c + 2], a.z, dot10);
            dot11 = fmaf(xr1[4 * c + 2], b.z, dot11);
            dot00 = fmaf(xr0[4 * c + 3], a.w, dot00);
            dot01 = fmaf(xr0[4 * c + 3], b.w, dot01);
            dot10 = fmaf(xr1[4 * c + 3], a.w, dot10);
            dot11 = fmaf(xr1[4 * c + 3], b.w, dot11);
        }
        float d00, d01, d10, d11;
        {
#pragma clang fp contract(off)
            const float e0 = esql[k + 0], e1 = esql[k + 1];
            d00 = (xsq0 + e0) - 2.0f * dot00;  // 2*dot exact; each op rounds
            d01 = (xsq0 + e1) - 2.0f * dot01;
            d10 = (xsq1 + e0) - 2.0f * dot10;
            d11 = (xsq1 + e1) - 2.0f * dot11;
        }
        // Lexicographic (d, k) min == ascending-k first-min-wins.
        // f32 equality is exact: identical bits from identical computation.
        if (d00 < best0 || (d00 == best0 && k     < bidx0)) { best0 = d00; bidx0 = k;     }
        if (d01 < best0 || (d01 == best0 && k + 1 < bidx0)) { best0 = d01; bidx0 = k + 1; }
        if (d10 < best1 || (d10 == best1 && k     < bidx1)) { best1 = d10; bidx1 = k;     }
        if (d11 < best1 || (d11 == best1 && k + 1 < bidx1)) { best1 = d11; bidx1 = k + 1; }
    }

    // ---- wave-cooperative coalesced epilogue (R3-proven), once per row-set ----
    // LDS gather: lane l reads cbs[idx*64 + l] -> 2-way bank aliasing = free.
    const size_t wave_row0 = (size_t)row0 - lane;
#pragma unroll 4
    for (int l = 0; l < 64; ++l) {
        const int idx = __shfl(bidx0, l, 64);
        out[1 + (wave_row0 + l) * DIM + lane] = cbs[idx * DIM + lane];
    }
    const size_t wave_row1 = (size_t)row1 - lane;
#pragma unroll 4
    for (int l = 0; l < 64; ++l) {
        const int idx = __shfl(bidx1, l, 64);
        out[1 + (wave_row1 + l) * DIM + lane] = cbs[idx * DIM + lane];
    }

    out[1 + (size_t)N_ROWS * DIM + row0] = (float)bidx0;  // coalesced
    out[1 + (size_t)N_ROWS * DIM + row1] = (float)bidx1;

    // loss contribution: sum of both rows' ||x - e||^2 (noise ~1e-5, thr ~2%)
    float lrow = best0 + best1;
#pragma unroll
    for (int off = 32; off > 0; off >>= 1) lrow += __shfl_down(lrow, off, 64);
    if (lane == 0) atomicAdd(loss_acc, lrow);
}

// ---- kernel 3: finalize loss ----
__global__ void fin_kernel(const float* __restrict__ loss_acc,
                           float* __restrict__ out) {
    if (threadIdx.x == 0) {
        float mean_sq = (*loss_acc) / (float)((size_t)N_ROWS * DIM);
        out[0] = 1.25f * mean_sq;  // q_loss + COMMITMENT_COST * e_loss
    }
}

extern "C" void kernel_launch(void* const* d_in, const int* in_sizes, int n_in,
                              void* d_out, int out_size, void* d_ws, size_t ws_size,
                              hipStream_t stream) {
    const float* x  = (const float*)d_in[0];
    const float* cb = (const float*)d_in[1];
    float* out = (float*)d_out;

    float* loss_acc = (float*)d_ws;                 // 4 B accumulator
    float* esq      = (float*)((char*)d_ws + 256);  // 512 floats

    hipMemsetAsync(d_ws, 0, 4, stream);             // zero loss accumulator
    esq_kernel<<<2, 256, 0, stream>>>(cb, esq);
    vq_kernel<<<N_ROWS / (BLK * RPT), BLK, LDS_FLOATS * sizeof(float), stream>>>(
        x, cb, esq, out, loss_acc);
    fin_kernel<<<1, 64, 0, stream>>>(loss_acc, out);
}

// Round 16
// 353.914 us; speedup vs baseline: 1.9470x; 1.9470x over previous
//
#include <hip/hip_runtime.h>
#include <hip/hip_bf16.h>

// Problem constants (fixed by reference): N=262144 rows, D=64, K=512 codes.
#define N_ROWS 262144
#define DIM 64
#define KC 512
#define BLK 512                        // threads/block; 8 waves = 2/SIMD, 1 block/CU
#define RPT 2                          // rows per thread
#define LDS_FLOATS (KC * DIM + KC)     // codebook + esq = 33280 floats = 133120 B

// d_out layout — FLOAT32 (verified passing):
//   out[0]                      = loss
//   out[1 .. 1+N*D)             = quantized [N,64] row-major
//   out[1+N*D .. 1+N*D+N)       = float(encoding_indices)
//
// Numerics replicated exactly (indices must match np.argmin of f32 dists):
//   x_sq, e_sq : numpy pairwise sum, n=64 => 8-accumulator striped scheme
//   dot        : sequential fused-FMA chain, ascending j (OpenBLAS kernel)
//   d          : fl( fl(x_sq + e_sq_k) - 2*dot_k ), contraction off
//   argmin     : strict <, first-min-wins (k ascending)
//
// R15 post-mortem: wave-stagger via masked circular k REGRESSED 276->652us
// (masked index killed the compiler's ds-offset pipelining; VALU busy rose
// to 271us). Reverted.
// R8 stall model: VALU busy 177us + DS 109us with ZERO overlap = 276us.
// Cause: compiler schedules each chunk's ds_read_b128 pair right before
// its consuming FMAs (~64cyc exposed latency per chunk; 2-wave TLP covers
// half). R10's ring had the right dataflow (consume chunk c, prefetch c+4
// = 128 issue-cyc distance) but the scheduler collapsed it.
// R16: R10 ring + sched_group_barrier pinning. Per chunk: SGB(DS_READ,2)
// + SGB(VALU,16) forces the emitted .s to alternate {2 ds_read, 16 fma}
// x16, preserving the 4-chunk read->use distance. Compile-time directive;
// numerics bit-identical to R8 (ring only renames registers).

#define SGB __builtin_amdgcn_sched_group_barrier
// LLVM SchedGroupMask: VALU=0x2, DS_READ=0x100 (per cdna guide T19 table)

// numpy pairwise sum of squares for n=64 (scalar path, PW_BLOCKSIZE=128).
__device__ __forceinline__ float np_sumsq64(const float* a) {
#pragma clang fp contract(off)
    float r[8];
#pragma unroll
    for (int j = 0; j < 8; ++j) r[j] = a[j] * a[j];
#pragma unroll
    for (int i = 8; i < 64; i += 8)
#pragma unroll
        for (int j = 0; j < 8; ++j) r[j] = r[j] + a[i + j] * a[i + j];
    return ((r[0] + r[1]) + (r[2] + r[3])) + ((r[4] + r[5]) + (r[6] + r[7]));
}

// ---- kernel 1: e_sq_k with numpy bit-exact summation ----
__global__ void esq_kernel(const float* __restrict__ cb, float* __restrict__ esq) {
    int k = blockIdx.x * blockDim.x + threadIdx.x;
    if (k < KC) esq[k] = np_sumsq64(cb + k * DIM);
}

// ---- kernel 2: main VQ — TWO rows per thread, LDS codebook, pinned ring ----
__global__ __launch_bounds__(BLK)
__attribute__((amdgpu_waves_per_eu(2, 2)))   // grid-exact occupancy; 256-VGPR budget
void vq_kernel(
    const float* __restrict__ x, const float* __restrict__ cb,
    const float* __restrict__ esq_g, float* __restrict__ out,
    float* __restrict__ loss_acc)
{
    extern __shared__ float smem[];
    float* cbs  = smem;             // [512*64] codebook, k-major (global layout)
    float* esql = smem + KC * DIM;  // [512]

    const int tid  = threadIdx.x;
    const int lane = tid & 63;
    const int row0 = blockIdx.x * (BLK * RPT) + tid;   // rows row0 and row0+BLK
    const int row1 = row0 + BLK;

    // ---- cooperative stage: 128KB codebook + 2KB esq, fully coalesced ----
    {
        const float4* g4 = reinterpret_cast<const float4*>(cb);
        float4*       s4 = reinterpret_cast<float4*>(cbs);
#pragma unroll
        for (int i = 0; i < (KC * DIM / 4) / BLK; ++i)   // 16 iters
            s4[tid + i * BLK] = g4[tid + i * BLK];
        if (tid < KC) esql[tid] = esq_g[tid];
    }

    // Two rows into 128 VGPRs — overlaps staging latency.
    float xr0[DIM], xr1[DIM];
    {
        const float4* xv0 = reinterpret_cast<const float4*>(x + (size_t)row0 * DIM);
        const float4* xv1 = reinterpret_cast<const float4*>(x + (size_t)row1 * DIM);
#pragma unroll
        for (int j = 0; j < DIM / 4; ++j) {
            float4 v0 = xv0[j], v1 = xv1[j];
            xr0[4 * j + 0] = v0.x; xr0[4 * j + 1] = v0.y;
            xr0[4 * j + 2] = v0.z; xr0[4 * j + 3] = v0.w;
            xr1[4 * j + 0] = v1.x; xr1[4 * j + 1] = v1.y;
            xr1[4 * j + 2] = v1.z; xr1[4 * j + 3] = v1.w;
        }
    }

    // numpy-exact ||x||^2 per row.
    const float xsq0 = np_sumsq64(xr0);
    const float xsq1 = np_sumsq64(xr1);

    __syncthreads();   // staging complete

    // Chunked view: code k = float4s cb4[k*16 .. k*16+15].
    const float4* cb4 = reinterpret_cast<const float4*>(cbs);

    // Prologue: chunks 0..3 of pair (codes 0, 1) into the ring.
    float4 sa[4], sb[4];
#pragma unroll
    for (int i = 0; i < 4; ++i) { sa[i] = cb4[i]; sb[i] = cb4[16 + i]; }

    // 2 codes x 2 rows per iter = 4 independent sequential fused-FMA chains.
    // Ring loads run 4 chunks (~128 issue-cyc) ahead; SGB pins the
    // {2 ds_read, 16 fma} alternation so the scheduler can't collapse it.
    float best0 = 3.4e38f, best1 = 3.4e38f;
    int bidx0 = 0, bidx1 = 0;
#pragma unroll 1
    for (int k = 0; k < KC; k += 2) {
        const float4* base = cb4 + (size_t)k * 16;   // [0..15]=code k, [16..31]=code k+1
        float dot00 = 0.f, dot01 = 0.f, dot10 = 0.f, dot11 = 0.f;
#pragma unroll
        for (int c = 0; c < 16; ++c) {               // fully unrolled: c compile-time
            const float4 a = sa[c & 3];
            const float4 b = sb[c & 3];
            // Prefetch chunk c+4 of this pair, or chunk c-12 of the NEXT pair.
            if (c < 12) {
                sa[c & 3] = base[c + 4];
                sb[c & 3] = base[16 + c + 4];
            } else {
                sa[c & 3] = base[32 + (c - 12)];     // next pair code k+2
                sb[c & 3] = base[48 + (c - 12)];     // next pair code k+3
            }
            // ascending j = 4c..4c+3 within each chain (bit-exact R8 order)
            dot00 = fmaf(xr0[4 * c + 0], a.x, dot00);
            dot01 = fmaf(xr0[4 * c + 0], b.x, dot01);
            dot10 = fmaf(xr1[4 * c + 0], a.x, dot10);
            dot11 = fmaf(xr1[4 * c + 0], b.x, dot11);
            dot00 = fmaf(xr0[4 * c + 1], a.y, dot00);
            dot01 = fmaf(xr0[4 * c + 1], b.y, dot01);
            dot10 = fmaf(xr1[4 * c + 1], a.y, dot10);
            dot11 = fmaf(xr1[4 * c + 1], b.y, dot11);
            dot00 = fmaf(xr0[4 * c + 2], a.z, dot00);
            dot01 = fmaf(xr0[4 * c + 2], b.z, dot01);
            dot10 = fmaf(xr1[4 * c + 2], a.z, dot10);
            dot11 = fmaf(xr1[4 * c + 2], b.z, dot11);
            dot00 = fmaf(xr0[4 * c + 3], a.w, dot00);
            dot01 = fmaf(xr0[4 * c + 3], b.w, dot01);
            dot10 = fmaf(xr1[4 * c + 3], a.w, dot10);
            dot11 = fmaf(xr1[4 * c + 3], b.w, dot11);
            // Pin: 2 LDS reads, then 16 FMAs, per chunk (in program order).
            SGB(0x100 /*DS_READ*/, 2, 0);
            SGB(0x002 /*VALU   */, 16, 0);
        }
        float d00, d01, d10, d11;
        {
#pragma clang fp contract(off)
            const float e0 = esql[k + 0], e1 = esql[k + 1];
            d00 = (xsq0 + e0) - 2.0f * dot00;  // 2*dot exact; each op rounds
            d01 = (xsq0 + e1) - 2.0f * dot01;
            d10 = (xsq1 + e0) - 2.0f * dot10;
            d11 = (xsq1 + e1) - 2.0f * dot11;
        }
        // strict <, ascending k: first-min-wins preserved (per row).
        if (d00 < best0) { best0 = d00; bidx0 = k + 0; }
        if (d01 < best0) { best0 = d01; bidx0 = k + 1; }
        if (d10 < best1) { best1 = d10; bidx1 = k + 0; }
        if (d11 < best1) { best1 = d11; bidx1 = k + 1; }
    }

    // ---- wave-cooperative coalesced epilogue (R3-proven), once per row-set ----
    // LDS gather: lane l reads cbs[idx*64 + l] -> 2-way bank aliasing = free.
    const size_t wave_row0 = (size_t)row0 - lane;
#pragma unroll 4
    for (int l = 0; l < 64; ++l) {
        const int idx = __shfl(bidx0, l, 64);
        out[1 + (wave_row0 + l) * DIM + lane] = cbs[idx * DIM + lane];
    }
    const size_t wave_row1 = (size_t)row1 - lane;
#pragma unroll 4
    for (int l = 0; l < 64; ++l) {
        const int idx = __shfl(bidx1, l, 64);
        out[1 + (wave_row1 + l) * DIM + lane] = cbs[idx * DIM + lane];
    }

    out[1 + (size_t)N_ROWS * DIM + row0] = (float)bidx0;  // coalesced
    out[1 + (size_t)N_ROWS * DIM + row1] = (float)bidx1;

    // loss contribution: sum of both rows' ||x - e||^2 (noise ~1e-5, thr ~2%)
    float lrow = best0 + best1;
#pragma unroll
    for (int off = 32; off > 0; off >>= 1) lrow += __shfl_down(lrow, off, 64);
    if (lane == 0) atomicAdd(loss_acc, lrow);
}

// ---- kernel 3: finalize loss ----
__global__ void fin_kernel(const float* __restrict__ loss_acc,
                           float* __restrict__ out) {
    if (threadIdx.x == 0) {
        float mean_sq = (*loss_acc) / (float)((size_t)N_ROWS * DIM);
        out[0] = 1.25f * mean_sq;  // q_loss + COMMITMENT_COST * e_loss
    }
}

extern "C" void kernel_launch(void* const* d_in, const int* in_sizes, int n_in,
                              void* d_out, int out_size, void* d_ws, size_t ws_size,
                              hipStream_t stream) {
    const float* x  = (const float*)d_in[0];
    const float* cb = (const float*)d_in[1];
    float* out = (float*)d_out;

    float* loss_acc = (float*)d_ws;                 // 4 B accumulator
    float* esq      = (float*)((char*)d_ws + 256);  // 512 floats

    hipMemsetAsync(d_ws, 0, 4, stream);             // zero loss accumulator
    esq_kernel<<<2, 256, 0, stream>>>(cb, esq);
    vq_kernel<<<N_ROWS / (BLK * RPT), BLK, LDS_FLOATS * sizeof(float), stream>>>(
        x, cb, esq, out, loss_acc);
    fin_kernel<<<1, 64, 0, stream>>>(loss_acc, out);
}